// Round 4
// baseline (435.521 us; speedup 1.0000x reference)
//
#include <hip/hip_runtime.h>

// ---------------------------------------------------------------------------
// MAF forward log-prob, fully fused. D=45, H=256, NB=6, L=2, K=8, M=23.
// R4: operand-swapped MFMA (weights=arg0 -> cols on regs, acts=arg1 -> rows on
// lanes): epilogue writes packed ds_write_b64 (4 consecutive cols per reg
// quad). Retile 2 row-groups x 4 col-pair-groups: activations ds_read_b128
// once per kt per wave. Spline params padded to stride 24 (16B-aligned) ->
// 3x ds_read_b128. zb eliminated (W0 B-frags built from zf f32, K=48).
// LDS 74240 B -> 2 WGs/CU. Spline: no max-sub, fast rcp, single log.
// ---------------------------------------------------------------------------

typedef __bf16 bf16;
typedef __bf16 bf16x4 __attribute__((ext_vector_type(4)));
typedef __bf16 bf16x8 __attribute__((ext_vector_type(8)));
typedef float  f32x4  __attribute__((ext_vector_type(4)));
typedef float  f32x16 __attribute__((ext_vector_type(16)));

#define TAILF  13.815510557964274f      /* -log(1e-6) */
#define LOGZ   41.352233994210265f      /* 0.5*45*log(2*pi) */

// ---------------- workspace layout (bytes) ----------------
// Packed weight chunks: chunk (tile t, kt) = 512 bf16; element (lane,j) =
// W[col = t*32 + (lane&31)][k = kt*16 + (lane>>5)*8 + j]. Used as MFMA arg0.
#define WS_W0M   0            /* bf16 [6][8 t][3 kt][512]    147456 */
#define WS_WHM   147456       /* bf16 [12][8 t][16 kt][512]  1572864 */
#define WS_WFM   1720320      /* bf16 [30][7 t][16 kt][512]  3440640 */
#define WS_BEFF  5160960      /* f32  [6][256]   6144 */
#define WS_BFP   5167104      /* f32  [30][224]  26880 (stride-24 features) */
#define WS_WCC   5193984      /* f32  [6][256]   6144 */
#define WS_NEED  5200128

#define N_W0  (6*8*3*512)       /* 73728   */
#define N_WH  (6*2*256*256)     /* 786432  */
#define N_WF  (30*7*16*512)     /* 1720320 */
#define N_PREP (N_W0 + N_WH + N_WF)

// ---------------- merged prep kernel (mask + cast + fragment-pack) ---------
__global__ void prep_all(const float* __restrict__ W0, const float* __restrict__ b0,
                         const float* __restrict__ Wc, const float* __restrict__ bc,
                         const float* __restrict__ Wh, const float* __restrict__ Wf,
                         const float* __restrict__ bfv,
                         bf16* __restrict__ W0m, bf16* __restrict__ Whm,
                         bf16* __restrict__ Wfm,
                         float* __restrict__ beff, float* __restrict__ bfp,
                         float* __restrict__ Wcc)
{
    int idx = blockIdx.x * 256 + threadIdx.x;
    if (idx < N_W0) {
        // [b][t=8][kt=3][512]
        int j = idx & 7, lane = (idx >> 3) & 63, chunk = idx >> 9;
        int kt = chunk % 3, t = (chunk / 3) & 7, b = chunk / 24;
        int col = t * 32 + (lane & 31);
        int k   = kt * 16 + (lane >> 5) * 8 + j;
        float v = 0.f;
        if (k < 45 && (col % 44) >= k)                 // m0: deg_h[col] >= k+1
            v = W0[(b * 256 + col) * 45 + k];
        W0m[idx] = (bf16)v;
        if (k == 0) {
            beff[b * 256 + col] = b0[b * 256 + col] + bc[b * 256 + col];
            Wcc[b * 256 + col]  = Wc[b * 256 + col];
        }
    } else if (idx < N_W0 + N_WH) {
        // [bl][t=8][kt=16][512]
        int id = idx - N_W0;
        int j = id & 7, lane = (id >> 3) & 63, chunk = id >> 9;
        int kt = chunk & 15, t = (chunk >> 4) & 7, bl = chunk >> 7;
        int col = t * 32 + (lane & 31);
        int k   = kt * 16 + (lane >> 5) * 8 + j;
        float v = ((col % 44) >= (k % 44)) ? Wh[bl * 65536 + col * 256 + k] : 0.f;
        Whm[id] = (bf16)v;
    } else if (idx < N_PREP) {
        // [bg][t=7][kt=16][512]; col 0..223; f = 9g + col/24, m = col%24
        int id = idx - (N_W0 + N_WH);
        int j = id & 7, lane = (id >> 3) & 63, chunk = id >> 9;
        int kt = chunk & 15, t2 = chunk >> 4;
        int t  = t2 % 7, bg = t2 / 7;                  // bg = b*5+g
        int b  = bg / 5, g = bg - 5 * b;
        int col = t * 32 + (lane & 31);
        int k   = kt * 16 + (lane >> 5) * 8 + j;
        int f   = 9 * g + col / 24;
        int m   = col - (col / 24) * 24;
        bool valid = (col < 216) && (m < 23);
        float v = 0.f;
        if (valid && (f > (k % 44)))                   // mf strict
            v = Wf[(b * 1035 + f * 23 + m) * 256 + k];
        Wfm[id] = (bf16)v;
        if (k == 0)
            bfp[bg * 224 + col] = valid ? bfv[b * 1035 + f * 23 + m] : 0.f;
    }
}

// ---------------- fused main kernel ----------------
// LDS (dynamic, 74240 B -> 2 blocks/CU):
#define SO_ZF    0        /* float [64][48]  12288 (cols 45..47 = 0) */
#define SO_HIDA  12288    /* bf16  [64][264] 33792 */
#define SO_PBUF  46080    /* bf16  [64][216] 27648 (stride-24 features) */
#define SO_COND  73728    /* float [64] */
#define SO_LD    73984    /* float [64] */
#define SMEM_BYTES 74240

// GEMM: out[64 rows][NT*32 cols] = act[64][KT*16] @ W^T (+epilogue).
// 8 waves = 2 row-groups x 4 col-pair-groups; wave: 32 rows x 2 col-tiles.
// MFMA(arg0=weight chunk, arg1=act frag): D lane&31=row, regs: col =
// t*32 + (r&3) + 8*(r>>2) + 4*(lane>>5)  -> reg quads = 4 consecutive cols
// -> packed bf16x4 ds_write_b64 epilogue.
// MODE 0: +bias+cond*wcol; MODE 1: +bias, relu; MODE 2: +bias.
template<int KT, int NT, int MODE, bool F32B, int LIMIT>
__device__ __forceinline__ void gemm32(
    const void* Bact, int ldb,
    const bf16* __restrict__ Wp,
    const float* __restrict__ bias, const float* __restrict__ wcol,
    float condv, bf16* dst, int ldd,
    int w, int lane, bool preEpiSync)
{
    const int cg  = w & 3;
    const int rg  = w >> 2;
    const int l31 = lane & 31;
    const int q   = lane >> 5;
    const int t0  = cg * 2, t1 = cg * 2 + 1;
    const bool has1 = (NT == 8) || (t1 < NT);
    const int row = rg * 32 + l31;

    const bf16*  Bp  = (const bf16*)Bact + row * ldb + q * 8;
    const float* Bpf = (const float*)Bact + row * ldb + q * 8;
    const bf16*  A0  = Wp + ((size_t)t0 * KT) * 512 + lane * 8;
    const bf16*  A1  = Wp + ((size_t)t1 * KT) * 512 + lane * 8;

    f32x16 acc0 = {}, acc1 = {};
    constexpr int CH = (KT < 4) ? KT : 4;
    #pragma unroll
    for (int kb = 0; kb < KT / CH; ++kb) {
        bf16x8 wq0[CH], wq1[CH];
        #pragma unroll
        for (int c = 0; c < CH; ++c) {
            wq0[c] = *reinterpret_cast<const bf16x8*>(A0 + (kb * CH + c) * 512);
            if (has1)
                wq1[c] = *reinterpret_cast<const bf16x8*>(A1 + (kb * CH + c) * 512);
        }
        #pragma unroll
        for (int c = 0; c < CH; ++c) {
            const int kt = kb * CH + c;
            bf16x8 bfrag;
            if constexpr (F32B) {
                f32x4 fa = *reinterpret_cast<const f32x4*>(Bpf + kt * 16);
                f32x4 fb = *reinterpret_cast<const f32x4*>(Bpf + kt * 16 + 4);
                bfrag = (bf16x8){(bf16)fa[0], (bf16)fa[1], (bf16)fa[2], (bf16)fa[3],
                                 (bf16)fb[0], (bf16)fb[1], (bf16)fb[2], (bf16)fb[3]};
            } else {
                bfrag = *reinterpret_cast<const bf16x8*>(Bp + kt * 16);
            }
            acc0 = __builtin_amdgcn_mfma_f32_32x32x16_bf16(wq0[c], bfrag, acc0, 0, 0, 0);
            if (has1)
                acc1 = __builtin_amdgcn_mfma_f32_32x32x16_bf16(wq1[c], bfrag, acc1, 0, 0, 0);
        }
    }

    if (preEpiSync) __syncthreads();   // in-place layers: all act reads done

    bf16* drow = dst + row * ldd;
    #pragma unroll
    for (int rr = 0; rr < 4; ++rr) {
        {
            const int colb = t0 * 32 + rr * 8 + q * 4;
            if (LIMIT == 256 || colb < LIMIT) {
                f32x4 bv = *reinterpret_cast<const f32x4*>(bias + colb);
                f32x4 wc = {};
                if (MODE == 0) wc = *reinterpret_cast<const f32x4*>(wcol + colb);
                bf16x4 pk;
                #pragma unroll
                for (int i = 0; i < 4; ++i) {
                    float v = acc0[rr * 4 + i] + bv[i];
                    if (MODE == 0) v += condv * wc[i];
                    if (MODE == 1) v = fmaxf(v, 0.f);
                    pk[i] = (bf16)v;
                }
                *reinterpret_cast<bf16x4*>(drow + colb) = pk;
            }
        }
        if (has1) {
            const int colb = t1 * 32 + rr * 8 + q * 4;
            if (LIMIT == 256 || colb < LIMIT) {
                f32x4 bv = *reinterpret_cast<const f32x4*>(bias + colb);
                f32x4 wc = {};
                if (MODE == 0) wc = *reinterpret_cast<const f32x4*>(wcol + colb);
                bf16x4 pk;
                #pragma unroll
                for (int i = 0; i < 4; ++i) {
                    float v = acc1[rr * 4 + i] + bv[i];
                    if (MODE == 0) v += condv * wc[i];
                    if (MODE == 1) v = fmaxf(v, 0.f);
                    pk[i] = (bf16)v;
                }
                *reinterpret_cast<bf16x4*>(drow + colb) = pk;
            }
        }
    }
    __syncthreads();
}

// RQ spline for 9 features starting at fb; params in pbuf (row stride 216,
// feature stride 24, 16B-aligned -> 3x ds_read_b128). Updates zf/ldl.
__device__ __forceinline__ void do_spline(int fb, float* zf,
                                          const bf16* pbuf, float* ldl, int t)
{
    for (int task = t; task < 64 * 9; task += 512) {
        int r  = task / 9;
        int fl = task - r * 9;
        const bf16* pp = pbuf + r * 216 + fl * 24;
        bf16x8 p0 = *reinterpret_cast<const bf16x8*>(pp);
        bf16x8 p1 = *reinterpret_cast<const bf16x8*>(pp + 8);
        bf16x8 p2 = *reinterpret_cast<const bf16x8*>(pp + 16);
        float P[24];
        #pragma unroll
        for (int m = 0; m < 8; ++m) {
            P[m]      = (float)p0[m];
            P[8 + m]  = (float)p1[m];
            P[16 + m] = (float)p2[m];
        }

        float xin = zf[r * 48 + fb + fl];
        float xc  = fminf(fmaxf(xin, -TAILF), TAILF);
        bool inside = (xin >= -TAILF) && (xin <= TAILF);

        // widths: softmax(P[0..7]/16), no max-sub (|P| << 1)
        float ew[8], sw = 0.f;
        #pragma unroll
        for (int i = 0; i < 8; ++i) { ew[i] = __expf(P[i] * 0.0625f); sw += ew[i]; }
        float rws = 0.992f * __frcp_rn(sw);
        float cw[9]; cw[0] = -TAILF;
        #pragma unroll
        for (int i = 0; i < 8; ++i)
            cw[i + 1] = cw[i] + 2.f * TAILF * (1e-3f + ew[i] * rws);
        cw[8] = TAILF;
        float wb[8];
        #pragma unroll
        for (int i = 0; i < 8; ++i) wb[i] = cw[i + 1] - cw[i];

        // heights
        float eh[8], sh = 0.f;
        #pragma unroll
        for (int i = 0; i < 8; ++i) { eh[i] = __expf(P[8 + i] * 0.0625f); sh += eh[i]; }
        float rhs = 0.992f * __frcp_rn(sh);
        float ch[9]; ch[0] = -TAILF;
        #pragma unroll
        for (int i = 0; i < 8; ++i)
            ch[i + 1] = ch[i] + 2.f * TAILF * (1e-3f + eh[i] * rhs);
        ch[8] = TAILF;
        float hb[8];
        #pragma unroll
        for (int i = 0; i < 8; ++i) hb[i] = ch[i + 1] - ch[i];

        // derivatives: d[0]=d[8]=1 (pad), d[i]=1e-3+softplus(P[15+i])
        float dd[9];
        dd[0] = 1.0f; dd[8] = 1.0f;
        #pragma unroll
        for (int i = 1; i < 8; ++i)
            dd[i] = 1e-3f + __logf(1.f + __expf(P[15 + i]));

        // bin select (unrolled scan)
        float icw = cw[0], ich = ch[0], ibw = wb[0], ibh = hb[0];
        float id0 = dd[0], id1 = dd[1];
        #pragma unroll
        for (int i = 1; i < 8; ++i) {
            bool ge = xc >= cw[i];
            icw = ge ? cw[i] : icw;  ich = ge ? ch[i] : ich;
            ibw = ge ? wb[i] : ibw;  ibh = ge ? hb[i] : ibh;
            id0 = ge ? dd[i] : id0;  id1 = ge ? dd[i + 1] : id1;
        }

        float ribw = __frcp_rn(ibw);
        float th   = (xc - icw) * ribw;
        float th1  = th * (1.f - th);
        float dl   = ibh * ribw;
        float den  = dl + (id0 + id1 - 2.f * dl) * th1;
        float rden = __frcp_rn(den);
        float yy   = ich + ibh * (dl * th * th + id0 * th1) * rden;
        float num  = dl * dl * (id1 * th * th + 2.f * dl * th1
                                + id0 * (1.f - th) * (1.f - th));
        float lad  = __logf(num * rden * rden);

        if (inside) {
            zf[r * 48 + fb + fl] = yy;
            atomicAdd(&ldl[r], lad);
        }
    }
}

__global__ __launch_bounds__(512, 4) void maf_main(
    const float* __restrict__ x, const float* __restrict__ cond,
    const float* __restrict__ bh_all,
    const bf16* __restrict__ W0m, const bf16* __restrict__ Whm,
    const bf16* __restrict__ Wfm,
    const float* __restrict__ beff, const float* __restrict__ bfp,
    const float* __restrict__ Wcc,
    float* __restrict__ out, int B)
{
    extern __shared__ char smem[];
    float* zf    = (float*)(smem + SO_ZF);
    bf16*  hidA  = (bf16*)(smem + SO_HIDA);
    bf16*  pbuf  = (bf16*)(smem + SO_PBUF);
    float* condl = (float*)(smem + SO_COND);
    float* ldl   = (float*)(smem + SO_LD);

    const int t    = threadIdx.x;
    const int r0   = blockIdx.x * 64;
    const int w    = t >> 6;
    const int lane = t & 63;

    // init: zf pad cols 45..47 zero, x -> zf, cond, ld
    for (int i = t; i < 64 * 3; i += 512) {
        int r = i / 3, c = i - (i / 3) * 3;
        zf[r * 48 + 45 + c] = 0.f;
    }
    for (int i = t; i < 64 * 45; i += 512) {
        int r = i / 45, f = i - (i / 45) * 45;
        zf[r * 48 + f] = (r0 + r < B) ? x[(size_t)(r0 + r) * 45 + f] : 0.f;
    }
    if (t < 64) {
        condl[t] = (r0 + t < B) ? cond[r0 + t] : 0.f;
        ldl[t]   = 0.f;
    }
    __syncthreads();

    const float condv = condl[(w >> 2) * 32 + (lane & 31)];

    #pragma unroll 1
    for (int b = 0; b < 6; ++b) {
        // input MADE layer: K=48 (padded from 45), B-frags from zf (f32)
        gemm32<3, 8, 0, true, 256>(zf, 48, W0m + b * 12288,
                                   beff + b * 256, Wcc + b * 256, condv,
                                   hidA, 264, w, lane, false);
        // 2 hidden layers, relu, in-place
        #pragma unroll 1
        for (int l = 0; l < 2; ++l)
            gemm32<16, 8, 1, false, 256>(hidA, 264, Whm + (b * 2 + l) * 65536,
                                         bh_all + (b * 2 + l) * 256, nullptr, 0.f,
                                         hidA, 264, w, lane, true);
        // params: 5 groups x 9 features (stride-24, 216 cols of 224)
        #pragma unroll 1
        for (int g = 0; g < 5; ++g) {
            gemm32<16, 7, 2, false, 216>(hidA, 264,
                                         Wfm + (size_t)(b * 5 + g) * 57344,
                                         bfp + (b * 5 + g) * 224, nullptr, 0.f,
                                         pbuf, 216, w, lane, false);
            do_spline(g * 9, zf, pbuf, ldl, t);
            __syncthreads();
        }
    }

    if (t < 64 && r0 + t < B) {
        float s = 0.f;
        #pragma unroll
        for (int f = 0; f < 45; ++f) { float v = zf[t * 48 + f]; s += v * v; }
        out[r0 + t] = -0.5f * s - LOGZ + ldl[t];
    }
}

// ---------------- host entry ----------------
extern "C" void kernel_launch(void* const* d_in, const int* in_sizes, int n_in,
                              void* d_out, int out_size, void* d_ws, size_t ws_size,
                              hipStream_t stream)
{
    const float* x    = (const float*)d_in[0];
    const float* cond = (const float*)d_in[1];
    const float* W0   = (const float*)d_in[2];
    const float* b0   = (const float*)d_in[3];
    const float* Wc   = (const float*)d_in[4];
    const float* bc   = (const float*)d_in[5];
    const float* Wh   = (const float*)d_in[6];
    const float* bh   = (const float*)d_in[7];
    const float* Wf   = (const float*)d_in[8];
    const float* bfv  = (const float*)d_in[9];
    float* out = (float*)d_out;

    const int B = in_sizes[0] / 45;
    if (ws_size < (size_t)WS_NEED) return;   // fail loudly

    char* ws = (char*)d_ws;
    bf16*  W0m  = (bf16*)(ws + WS_W0M);
    bf16*  Whm  = (bf16*)(ws + WS_WHM);
    bf16*  Wfm  = (bf16*)(ws + WS_WFM);
    float* beff = (float*)(ws + WS_BEFF);
    float* bfp  = (float*)(ws + WS_BFP);
    float* Wcc  = (float*)(ws + WS_WCC);

    prep_all<<<(N_PREP + 255) / 256, 256, 0, stream>>>(
        W0, b0, Wc, bc, Wh, Wf, bfv, W0m, Whm, Wfm, beff, bfp, Wcc);

    (void)hipFuncSetAttribute((const void*)maf_main,
                              hipFuncAttributeMaxDynamicSharedMemorySize,
                              SMEM_BYTES);

    const int nwg = (B + 63) / 64;
    maf_main<<<nwg, 512, SMEM_BYTES, stream>>>(
        x, cond, bh, W0m, Whm, Wfm, beff, bfp, Wcc, out, B);
}

// Round 5
// 399.085 us; speedup vs baseline: 1.0913x; 1.0913x over previous
//
#include <hip/hip_runtime.h>

// ---------------------------------------------------------------------------
// MAF forward log-prob, fully fused. D=45, H=256, NB=6, L=2, K=8, M=23.
// R5: R3's proven access patterns (acts=arg0 via LDS b128, weights=arg1 via
// coalesced packed global chunks, scalar col-consecutive b16 epilogue) +
// occupancy restructure: 32 rows / 512-thr WG (8 waves x one 32-col tile),
// LDS 37.1 KB -> 4 WGs/CU -> 32 waves/CU. Spline: R4 math trims + b128
// param reads (stride-24). zb eliminated (L0 A-frags built from f32 zf).
// ---------------------------------------------------------------------------

typedef __bf16 bf16;
typedef __bf16 bf16x8 __attribute__((ext_vector_type(8)));
typedef float  f32x4  __attribute__((ext_vector_type(4)));
typedef float  f32x16 __attribute__((ext_vector_type(16)));

#define TAILF  13.815510557964274f      /* -log(1e-6) */
#define LOGZ   41.352233994210265f      /* 0.5*45*log(2*pi) */

// ---------------- workspace layout (bytes) ----------------
// Packed weight chunks: chunk (tile t, kt) = 512 bf16; element (lane,j) =
// W[col = t*32 + (lane&31)][k = kt*16 + (lane>>5)*8 + j].  (A- and B-frag
// layouts share this formula, so packing is operand-position agnostic.)
#define WS_W0M   0            /* bf16 [6][8 t][3 kt][512]    147456 */
#define WS_WHM   147456       /* bf16 [12][8 t][16 kt][512]  1572864 */
#define WS_WFM   1720320      /* bf16 [30][7 t][16 kt][512]  3440640 */
#define WS_BEFF  5160960      /* f32  [6][256]   6144 */
#define WS_BFP   5167104      /* f32  [30][224]  26880 (stride-24 features) */
#define WS_WCC   5193984      /* f32  [6][256]   6144 */
#define WS_NEED  5200128

#define N_W0  (6*8*3*512)       /* 73728   */
#define N_WH  (6*2*256*256)     /* 786432  */
#define N_WF  (30*7*16*512)     /* 1720320 */
#define N_PREP (N_W0 + N_WH + N_WF)

// ---------------- merged prep kernel (mask + cast + fragment-pack) ---------
__global__ void prep_all(const float* __restrict__ W0, const float* __restrict__ b0,
                         const float* __restrict__ Wc, const float* __restrict__ bc,
                         const float* __restrict__ Wh, const float* __restrict__ Wf,
                         const float* __restrict__ bfv,
                         bf16* __restrict__ W0m, bf16* __restrict__ Whm,
                         bf16* __restrict__ Wfm,
                         float* __restrict__ beff, float* __restrict__ bfp,
                         float* __restrict__ Wcc)
{
    int idx = blockIdx.x * 256 + threadIdx.x;
    if (idx < N_W0) {
        // [b][t=8][kt=3][512]
        int j = idx & 7, lane = (idx >> 3) & 63, chunk = idx >> 9;
        int kt = chunk % 3, t = (chunk / 3) & 7, b = chunk / 24;
        int col = t * 32 + (lane & 31);
        int k   = kt * 16 + (lane >> 5) * 8 + j;
        float v = 0.f;
        if (k < 45 && (col % 44) >= k)                 // m0: deg_h[col] >= k+1
            v = W0[(b * 256 + col) * 45 + k];
        W0m[idx] = (bf16)v;
        if (k == 0) {
            beff[b * 256 + col] = b0[b * 256 + col] + bc[b * 256 + col];
            Wcc[b * 256 + col]  = Wc[b * 256 + col];
        }
    } else if (idx < N_W0 + N_WH) {
        // [bl][t=8][kt=16][512]
        int id = idx - N_W0;
        int j = id & 7, lane = (id >> 3) & 63, chunk = id >> 9;
        int kt = chunk & 15, t = (chunk >> 4) & 7, bl = chunk >> 7;
        int col = t * 32 + (lane & 31);
        int k   = kt * 16 + (lane >> 5) * 8 + j;
        float v = ((col % 44) >= (k % 44)) ? Wh[bl * 65536 + col * 256 + k] : 0.f;
        Whm[id] = (bf16)v;
    } else if (idx < N_PREP) {
        // [bg][t=7][kt=16][512]; col 0..223; f = 9g + col/24, m = col%24
        int id = idx - (N_W0 + N_WH);
        int j = id & 7, lane = (id >> 3) & 63, chunk = id >> 9;
        int kt = chunk & 15, t2 = chunk >> 4;
        int t  = t2 % 7, bg = t2 / 7;                  // bg = b*5+g
        int b  = bg / 5, g = bg - 5 * b;
        int col = t * 32 + (lane & 31);
        int k   = kt * 16 + (lane >> 5) * 8 + j;
        int f   = 9 * g + col / 24;
        int m   = col - (col / 24) * 24;
        bool valid = (col < 216) && (m < 23);
        float v = 0.f;
        if (valid && (f > (k % 44)))                   // mf strict
            v = Wf[(b * 1035 + f * 23 + m) * 256 + k];
        Wfm[id] = (bf16)v;
        if (k == 0)
            bfp[bg * 224 + col] = valid ? bfv[b * 1035 + f * 23 + m] : 0.f;
    }
}

// ---------------- fused main kernel ----------------
// LDS (dynamic, 37120 B -> 4 blocks/CU):
#define SO_ZF    0        /* float [32][48]   6144 (cols 45..47 = 0) */
#define SO_HIDA  6144     /* bf16  [32][264] 16896 */
#define SO_PBUF  23040    /* bf16  [32][216] 13824 (stride-24 features) */
#define SO_COND  36864    /* float [32] */
#define SO_LD    36992    /* float [32] */
#define SMEM_BYTES 37120

// GEMM: out[32 rows][NT*32 cols] = act[32][KT*16] @ W^T (+epilogue).
// 8 waves, wave w owns col tile w (32 cols), all 32 rows in one acc.
// arg0 = act frag (LDS b128 / f32-built): A[m=lane&31][k=(lane>>5)*8+j];
// arg1 = weight chunk (coalesced global, lane*16B);
// D: col(n)=lane&31, row(m)=(r&3)+8*(r>>2)+4*(lane>>5).
// MODE 0: +bias+cond[row]*wcol; MODE 1: +bias, relu; MODE 2: +bias.
template<int KT, int NT, int MODE, bool F32B, int LIMIT>
__device__ __forceinline__ void gemm32(
    const void* Act, int lda,
    const bf16* __restrict__ Wp,
    const float* __restrict__ bias, const float* __restrict__ wcol,
    const float* condl, bf16* dst, int ldd,
    int w, int lane, bool preEpiSync)
{
    const bool act = (NT == 8) || (w < NT);
    const int  l31 = lane & 31;
    const int  q   = lane >> 5;

    const bf16*  Ab = (const bf16*)Act + l31 * lda + q * 8;
    const float* Af = (const float*)Act + l31 * lda + q * 8;
    const bf16*  Bp = Wp + (size_t)w * KT * 512 + lane * 8;

    f32x16 acc = {};
    constexpr int CH = (KT < 4) ? KT : 4;
    #pragma unroll
    for (int kb = 0; kb < KT / CH; ++kb) {
        bf16x8 wq[CH];
        if (act) {
            #pragma unroll
            for (int c = 0; c < CH; ++c)
                wq[c] = *reinterpret_cast<const bf16x8*>(Bp + (kb * CH + c) * 512);
            #pragma unroll
            for (int c = 0; c < CH; ++c) {
                const int kt = kb * CH + c;
                bf16x8 af;
                if constexpr (F32B) {
                    f32x4 fa = *reinterpret_cast<const f32x4*>(Af + kt * 16);
                    f32x4 fb = *reinterpret_cast<const f32x4*>(Af + kt * 16 + 4);
                    af = (bf16x8){(bf16)fa[0], (bf16)fa[1], (bf16)fa[2], (bf16)fa[3],
                                  (bf16)fb[0], (bf16)fb[1], (bf16)fb[2], (bf16)fb[3]};
                } else {
                    af = *reinterpret_cast<const bf16x8*>(Ab + kt * 16);
                }
                acc = __builtin_amdgcn_mfma_f32_32x32x16_bf16(af, wq[c], acc, 0, 0, 0);
            }
        }
    }

    if (preEpiSync) __syncthreads();   // in-place layers: all act reads done

    if (act) {
        const int col = w * 32 + l31;
        if (LIMIT == 256 || col < LIMIT) {
            const float bv  = bias[col];
            const float wcv = (MODE == 0) ? wcol[col] : 0.f;
            bf16* dcol = dst + col;
            #pragma unroll
            for (int r = 0; r < 16; ++r) {
                const int row = (r & 3) + 8 * (r >> 2) + 4 * q;
                float v = acc[r] + bv;
                if (MODE == 0) v += condl[row] * wcv;
                if (MODE == 1) v = fmaxf(v, 0.f);
                dcol[row * ldd] = (bf16)v;
            }
        }
    }
    __syncthreads();
}

// RQ spline for 9 features starting at fb; params in pbuf (row stride 216,
// feature stride 24, 16B-aligned -> 3x ds_read_b128). 288 tasks, one shot.
__device__ __forceinline__ void do_spline(int fb, float* zf,
                                          const bf16* pbuf, float* ldl, int t)
{
    if (t < 32 * 9) {
        int r  = t / 9;
        int fl = t - r * 9;
        const bf16* pp = pbuf + r * 216 + fl * 24;
        bf16x8 p0 = *reinterpret_cast<const bf16x8*>(pp);
        bf16x8 p1 = *reinterpret_cast<const bf16x8*>(pp + 8);
        bf16x8 p2 = *reinterpret_cast<const bf16x8*>(pp + 16);
        float P[24];
        #pragma unroll
        for (int m = 0; m < 8; ++m) {
            P[m]      = (float)p0[m];
            P[8 + m]  = (float)p1[m];
            P[16 + m] = (float)p2[m];
        }

        float xin = zf[r * 48 + fb + fl];
        float xc  = fminf(fmaxf(xin, -TAILF), TAILF);
        bool inside = (xin >= -TAILF) && (xin <= TAILF);

        // widths: softmax(P[0..7]/16), no max-sub (|P| << 1 by construction)
        float ew[8], sw = 0.f;
        #pragma unroll
        for (int i = 0; i < 8; ++i) { ew[i] = __expf(P[i] * 0.0625f); sw += ew[i]; }
        float rws = 0.992f * __frcp_rn(sw);
        float cw[9]; cw[0] = -TAILF;
        #pragma unroll
        for (int i = 0; i < 8; ++i)
            cw[i + 1] = cw[i] + 2.f * TAILF * (1e-3f + ew[i] * rws);
        cw[8] = TAILF;
        float wb[8];
        #pragma unroll
        for (int i = 0; i < 8; ++i) wb[i] = cw[i + 1] - cw[i];

        // heights
        float eh[8], sh = 0.f;
        #pragma unroll
        for (int i = 0; i < 8; ++i) { eh[i] = __expf(P[8 + i] * 0.0625f); sh += eh[i]; }
        float rhs = 0.992f * __frcp_rn(sh);
        float ch[9]; ch[0] = -TAILF;
        #pragma unroll
        for (int i = 0; i < 8; ++i)
            ch[i + 1] = ch[i] + 2.f * TAILF * (1e-3f + eh[i] * rhs);
        ch[8] = TAILF;
        float hb[8];
        #pragma unroll
        for (int i = 0; i < 8; ++i) hb[i] = ch[i + 1] - ch[i];

        // derivatives: d[0]=d[8]=1 (pad const), d[i]=1e-3+softplus(P[15+i])
        float dd[9];
        dd[0] = 1.0f; dd[8] = 1.0f;
        #pragma unroll
        for (int i = 1; i < 8; ++i)
            dd[i] = 1e-3f + __logf(1.f + __expf(P[15 + i]));

        // bin select (unrolled scan)
        float icw = cw[0], ich = ch[0], ibw = wb[0], ibh = hb[0];
        float id0 = dd[0], id1 = dd[1];
        #pragma unroll
        for (int i = 1; i < 8; ++i) {
            bool ge = xc >= cw[i];
            icw = ge ? cw[i] : icw;  ich = ge ? ch[i] : ich;
            ibw = ge ? wb[i] : ibw;  ibh = ge ? hb[i] : ibh;
            id0 = ge ? dd[i] : id0;  id1 = ge ? dd[i + 1] : id1;
        }

        float ribw = __frcp_rn(ibw);
        float th   = (xc - icw) * ribw;
        float th1  = th * (1.f - th);
        float dl   = ibh * ribw;
        float den  = dl + (id0 + id1 - 2.f * dl) * th1;
        float rden = __frcp_rn(den);
        float yy   = ich + ibh * (dl * th * th + id0 * th1) * rden;
        float num  = dl * dl * (id1 * th * th + 2.f * dl * th1
                                + id0 * (1.f - th) * (1.f - th));
        float lad  = __logf(num * rden * rden);

        if (inside) {
            zf[r * 48 + fb + fl] = yy;
            atomicAdd(&ldl[r], lad);
        }
    }
}

__global__ __launch_bounds__(512, 8) void maf_main(
    const float* __restrict__ x, const float* __restrict__ cond,
    const float* __restrict__ bh_all,
    const bf16* __restrict__ W0m, const bf16* __restrict__ Whm,
    const bf16* __restrict__ Wfm,
    const float* __restrict__ beff, const float* __restrict__ bfp,
    const float* __restrict__ Wcc,
    float* __restrict__ out, int B)
{
    extern __shared__ char smem[];
    float* zf    = (float*)(smem + SO_ZF);
    bf16*  hidA  = (bf16*)(smem + SO_HIDA);
    bf16*  pbuf  = (bf16*)(smem + SO_PBUF);
    float* condl = (float*)(smem + SO_COND);
    float* ldl   = (float*)(smem + SO_LD);

    const int t    = threadIdx.x;
    const int r0   = blockIdx.x * 32;
    const int w    = t >> 6;
    const int lane = t & 63;

    // init: zf (pad cols 45..47 = 0), cond, ld
    for (int i = t; i < 32 * 48; i += 512) {
        int r = i / 48, c = i - (i / 48) * 48;
        float v = 0.f;
        if (c < 45 && r0 + r < B) v = x[(size_t)(r0 + r) * 45 + c];
        zf[i] = v;
    }
    if (t < 32) {
        condl[t] = (r0 + t < B) ? cond[r0 + t] : 0.f;
        ldl[t]   = 0.f;
    }
    __syncthreads();

    #pragma unroll 1
    for (int b = 0; b < 6; ++b) {
        // input MADE layer: K=48 (padded from 45), A-frags from zf (f32)
        gemm32<3, 8, 0, true, 256>(zf, 48, W0m + b * 12288,
                                   beff + b * 256, Wcc + b * 256, condl,
                                   hidA, 264, w, lane, false);
        // 2 hidden layers, relu, in-place
        #pragma unroll 1
        for (int l = 0; l < 2; ++l)
            gemm32<16, 8, 1, false, 256>(hidA, 264, Whm + (b * 2 + l) * 65536,
                                         bh_all + (b * 2 + l) * 256, nullptr,
                                         nullptr, hidA, 264, w, lane, true);
        // params: 5 groups x 9 features (stride-24, cols 0..215 valid)
        #pragma unroll 1
        for (int g = 0; g < 5; ++g) {
            gemm32<16, 7, 2, false, 216>(hidA, 264,
                                         Wfm + (size_t)(b * 5 + g) * 57344,
                                         bfp + (b * 5 + g) * 224, nullptr,
                                         nullptr, pbuf, 216, w, lane, false);
            do_spline(g * 9, zf, pbuf, ldl, t);
            __syncthreads();
        }
    }

    if (t < 32 && r0 + t < B) {
        float s = 0.f;
        #pragma unroll
        for (int f = 0; f < 45; ++f) { float v = zf[t * 48 + f]; s += v * v; }
        out[r0 + t] = -0.5f * s - LOGZ + ldl[t];
    }
}

// ---------------- host entry ----------------
extern "C" void kernel_launch(void* const* d_in, const int* in_sizes, int n_in,
                              void* d_out, int out_size, void* d_ws, size_t ws_size,
                              hipStream_t stream)
{
    const float* x    = (const float*)d_in[0];
    const float* cond = (const float*)d_in[1];
    const float* W0   = (const float*)d_in[2];
    const float* b0   = (const float*)d_in[3];
    const float* Wc   = (const float*)d_in[4];
    const float* bc   = (const float*)d_in[5];
    const float* Wh   = (const float*)d_in[6];
    const float* bh   = (const float*)d_in[7];
    const float* Wf   = (const float*)d_in[8];
    const float* bfv  = (const float*)d_in[9];
    float* out = (float*)d_out;

    const int B = in_sizes[0] / 45;
    if (ws_size < (size_t)WS_NEED) return;   // fail loudly

    char* ws = (char*)d_ws;
    bf16*  W0m  = (bf16*)(ws + WS_W0M);
    bf16*  Whm  = (bf16*)(ws + WS_WHM);
    bf16*  Wfm  = (bf16*)(ws + WS_WFM);
    float* beff = (float*)(ws + WS_BEFF);
    float* bfp  = (float*)(ws + WS_BFP);
    float* Wcc  = (float*)(ws + WS_WCC);

    prep_all<<<(N_PREP + 255) / 256, 256, 0, stream>>>(
        W0, b0, Wc, bc, Wh, Wf, bfv, W0m, Whm, Wfm, beff, bfp, Wcc);

    (void)hipFuncSetAttribute((const void*)maf_main,
                              hipFuncAttributeMaxDynamicSharedMemorySize,
                              SMEM_BYTES);

    const int nwg = (B + 31) / 32;
    maf_main<<<nwg, 512, SMEM_BYTES, stream>>>(
        x, cond, bh, W0m, Whm, Wfm, beff, bfp, Wcc, out, B);
}

// Round 6
// 386.367 us; speedup vs baseline: 1.1272x; 1.0329x over previous
//
#include <hip/hip_runtime.h>

// ---------------------------------------------------------------------------
// MAF forward log-prob, fully fused. D=45, H=256, NB=6, L=2, K=8, M=23.
// R6: R5 structure (32 rows / 512-thr WG, 8 waves x one 32-col tile,
// LDS 37.1 KB -> 4 WGs/CU) with spills eliminated:
//  - spline rewritten as fused cumsum+select scans (~25 live regs vs ~100)
//  - weight-burst CH=2 (TLP from 32 waves/CU covers latency)
// R5 post-mortem: __launch_bounds__(512,8) + high-liveness spline => scratch
// spills (WRITE_SIZE 73 MB, FETCH 164 MB) that dominated runtime.
// ---------------------------------------------------------------------------

typedef __bf16 bf16;
typedef __bf16 bf16x8 __attribute__((ext_vector_type(8)));
typedef float  f32x4  __attribute__((ext_vector_type(4)));
typedef float  f32x16 __attribute__((ext_vector_type(16)));

#define TAILF  13.815510557964274f      /* -log(1e-6) */
#define LOGZ   41.352233994210265f      /* 0.5*45*log(2*pi) */

// ---------------- workspace layout (bytes) ----------------
// Packed weight chunks: chunk (tile t, kt) = 512 bf16; element (lane,j) =
// W[col = t*32 + (lane&31)][k = kt*16 + (lane>>5)*8 + j].
#define WS_W0M   0            /* bf16 [6][8 t][3 kt][512]    147456 */
#define WS_WHM   147456       /* bf16 [12][8 t][16 kt][512]  1572864 */
#define WS_WFM   1720320      /* bf16 [30][7 t][16 kt][512]  3440640 */
#define WS_BEFF  5160960      /* f32  [6][256]   6144 */
#define WS_BFP   5167104      /* f32  [30][224]  26880 (stride-24 features) */
#define WS_WCC   5193984      /* f32  [6][256]   6144 */
#define WS_NEED  5200128

#define N_W0  (6*8*3*512)       /* 73728   */
#define N_WH  (6*2*256*256)     /* 786432  */
#define N_WF  (30*7*16*512)     /* 1720320 */
#define N_PREP (N_W0 + N_WH + N_WF)

// ---------------- merged prep kernel (mask + cast + fragment-pack) ---------
__global__ void prep_all(const float* __restrict__ W0, const float* __restrict__ b0,
                         const float* __restrict__ Wc, const float* __restrict__ bc,
                         const float* __restrict__ Wh, const float* __restrict__ Wf,
                         const float* __restrict__ bfv,
                         bf16* __restrict__ W0m, bf16* __restrict__ Whm,
                         bf16* __restrict__ Wfm,
                         float* __restrict__ beff, float* __restrict__ bfp,
                         float* __restrict__ Wcc)
{
    int idx = blockIdx.x * 256 + threadIdx.x;
    if (idx < N_W0) {
        // [b][t=8][kt=3][512]
        int j = idx & 7, lane = (idx >> 3) & 63, chunk = idx >> 9;
        int kt = chunk % 3, t = (chunk / 3) & 7, b = chunk / 24;
        int col = t * 32 + (lane & 31);
        int k   = kt * 16 + (lane >> 5) * 8 + j;
        float v = 0.f;
        if (k < 45 && (col % 44) >= k)                 // m0: deg_h[col] >= k+1
            v = W0[(b * 256 + col) * 45 + k];
        W0m[idx] = (bf16)v;
        if (k == 0) {
            beff[b * 256 + col] = b0[b * 256 + col] + bc[b * 256 + col];
            Wcc[b * 256 + col]  = Wc[b * 256 + col];
        }
    } else if (idx < N_W0 + N_WH) {
        // [bl][t=8][kt=16][512]
        int id = idx - N_W0;
        int j = id & 7, lane = (id >> 3) & 63, chunk = id >> 9;
        int kt = chunk & 15, t = (chunk >> 4) & 7, bl = chunk >> 7;
        int col = t * 32 + (lane & 31);
        int k   = kt * 16 + (lane >> 5) * 8 + j;
        float v = ((col % 44) >= (k % 44)) ? Wh[bl * 65536 + col * 256 + k] : 0.f;
        Whm[id] = (bf16)v;
    } else if (idx < N_PREP) {
        // [bg][t=7][kt=16][512]; col 0..223; f = 9g + col/24, m = col%24
        int id = idx - (N_W0 + N_WH);
        int j = id & 7, lane = (id >> 3) & 63, chunk = id >> 9;
        int kt = chunk & 15, t2 = chunk >> 4;
        int t  = t2 % 7, bg = t2 / 7;                  // bg = b*5+g
        int b  = bg / 5, g = bg - 5 * b;
        int col = t * 32 + (lane & 31);
        int k   = kt * 16 + (lane >> 5) * 8 + j;
        int f   = 9 * g + col / 24;
        int m   = col - (col / 24) * 24;
        bool valid = (col < 216) && (m < 23);
        float v = 0.f;
        if (valid && (f > (k % 44)))                   // mf strict
            v = Wf[(b * 1035 + f * 23 + m) * 256 + k];
        Wfm[id] = (bf16)v;
        if (k == 0)
            bfp[bg * 224 + col] = valid ? bfv[b * 1035 + f * 23 + m] : 0.f;
    }
}

// ---------------- fused main kernel ----------------
// LDS (dynamic, 37120 B -> 4 blocks/CU):
#define SO_ZF    0        /* float [32][48]   6144 (cols 45..47 = 0) */
#define SO_HIDA  6144     /* bf16  [32][264] 16896 */
#define SO_PBUF  23040    /* bf16  [32][216] 13824 (stride-24 features) */
#define SO_COND  36864    /* float [32] */
#define SO_LD    36992    /* float [32] */
#define SMEM_BYTES 37120

// GEMM: out[32 rows][NT*32 cols] = act[32][KT*16] @ W^T (+epilogue).
// 8 waves, wave w owns col tile w (32 cols), all 32 rows in one acc.
// arg0 = act frag (LDS b128 / f32-built): A[m=lane&31][k=(lane>>5)*8+j];
// arg1 = weight chunk (coalesced global, lane*16B);
// D: col(n)=lane&31, row(m)=(r&3)+8*(r>>2)+4*(lane>>5).
// MODE 0: +bias+cond[row]*wcol; MODE 1: +bias, relu; MODE 2: +bias.
template<int KT, int NT, int MODE, bool F32B, int LIMIT>
__device__ __forceinline__ void gemm32(
    const void* Act, int lda,
    const bf16* __restrict__ Wp,
    const float* __restrict__ bias, const float* __restrict__ wcol,
    const float* condl, bf16* dst, int ldd,
    int w, int lane, bool preEpiSync)
{
    const bool act = (NT == 8) || (w < NT);
    const int  l31 = lane & 31;
    const int  q   = lane >> 5;

    const bf16*  Ab = (const bf16*)Act + l31 * lda + q * 8;
    const float* Af = (const float*)Act + l31 * lda + q * 8;
    const bf16*  Bp = Wp + (size_t)w * KT * 512 + lane * 8;

    f32x16 acc = {};
    constexpr int CH = (KT & 1) ? KT : 2;              // small burst: low VGPR
    #pragma unroll
    for (int kb = 0; kb < KT / CH; ++kb) {
        bf16x8 wq[CH];
        if (act) {
            #pragma unroll
            for (int c = 0; c < CH; ++c)
                wq[c] = *reinterpret_cast<const bf16x8*>(Bp + (kb * CH + c) * 512);
            #pragma unroll
            for (int c = 0; c < CH; ++c) {
                const int kt = kb * CH + c;
                bf16x8 af;
                if constexpr (F32B) {
                    f32x4 fa = *reinterpret_cast<const f32x4*>(Af + kt * 16);
                    f32x4 fb = *reinterpret_cast<const f32x4*>(Af + kt * 16 + 4);
                    af = (bf16x8){(bf16)fa[0], (bf16)fa[1], (bf16)fa[2], (bf16)fa[3],
                                  (bf16)fb[0], (bf16)fb[1], (bf16)fb[2], (bf16)fb[3]};
                } else {
                    af = *reinterpret_cast<const bf16x8*>(Ab + kt * 16);
                }
                acc = __builtin_amdgcn_mfma_f32_32x32x16_bf16(af, wq[c], acc, 0, 0, 0);
            }
        }
    }

    if (preEpiSync) __syncthreads();   // in-place layers: all act reads done

    if (act) {
        const int col = w * 32 + l31;
        if (LIMIT == 256 || col < LIMIT) {
            const float bv  = bias[col];
            const float wcv = (MODE == 0) ? wcol[col] : 0.f;
            bf16* dcol = dst + col;
            #pragma unroll
            for (int r = 0; r < 16; ++r) {
                const int row = (r & 3) + 8 * (r >> 2) + 4 * q;
                float v = acc[r] + bv;
                if (MODE == 0) v += condl[row] * wcv;
                if (MODE == 1) v = fmaxf(v, 0.f);
                dcol[row * ldd] = (bf16)v;
            }
        }
    }
    __syncthreads();
}

// RQ spline, low-register form: fused cumsum+select scans, ~25 live floats.
// Params in pbuf (row stride 216, feature stride 24 -> 3x ds_read_b128).
__device__ __forceinline__ void do_spline(int fb, float* zf,
                                          const bf16* pbuf, float* ldl, int t)
{
    if (t < 32 * 9) {
        int r  = t / 9;
        int fl = t - r * 9;
        const bf16* pp = pbuf + r * 216 + fl * 24;

        float xin = zf[r * 48 + fb + fl];
        float xc  = fminf(fmaxf(xin, -TAILF), TAILF);
        bool inside = (xin >= -TAILF) && (xin <= TAILF);

        // ---- widths: softmax(P/16) (no max-sub: |P|<<1), scan + bin select
        bf16x8 p0 = *reinterpret_cast<const bf16x8*>(pp);
        float ew[8], sw = 0.f;
        #pragma unroll
        for (int i = 0; i < 8; ++i) {
            ew[i] = __expf((float)p0[i] * 0.0625f); sw += ew[i];
        }
        float rws = 0.992f * __frcp_rn(sw);
        int   idx = 0;
        float icw = -TAILF, ibw = 1.f;
        {
            float left = -TAILF;
            #pragma unroll
            for (int i = 0; i < 8; ++i) {
                float wi = (i < 7) ? 2.f * TAILF * (1e-3f + ew[i] * rws)
                                   : (TAILF - left);
                bool ge = (xc >= left);          // left == cw[i] here
                idx = ge ? i : idx;
                icw = ge ? left : icw;
                ibw = ge ? wi : ibw;
                left += wi;
            }
        }

        // ---- heights: same scan, select bin i == idx
        bf16x8 p1 = *reinterpret_cast<const bf16x8*>(pp + 8);
        float eh[8], sh = 0.f;
        #pragma unroll
        for (int i = 0; i < 8; ++i) {
            eh[i] = __expf((float)p1[i] * 0.0625f); sh += eh[i];
        }
        float rhs = 0.992f * __frcp_rn(sh);
        float ich = -TAILF, ibh = 1.f;
        {
            float left = -TAILF;
            #pragma unroll
            for (int i = 0; i < 8; ++i) {
                float hi = (i < 7) ? 2.f * TAILF * (1e-3f + eh[i] * rhs)
                                   : (TAILF - left);
                bool eq = (i == idx);
                ich = eq ? left : ich;
                ibh = eq ? hi : ibh;
                left += hi;
            }
        }

        // ---- derivatives: d[0]=d[8]=1 (pad), interior 1e-3+softplus
        bf16x8 p2 = *reinterpret_cast<const bf16x8*>(pp + 16);
        float id0 = 1.f, id1 = 1.f;
        #pragma unroll
        for (int i = 1; i < 8; ++i) {
            float di = 1e-3f + __logf(1.f + __expf((float)p2[i - 1]));
            id0 = (i == idx) ? di : id0;
            id1 = (i == idx + 1) ? di : id1;
        }

        float ribw = __frcp_rn(ibw);
        float th   = (xc - icw) * ribw;
        float th1  = th * (1.f - th);
        float dl   = ibh * ribw;
        float den  = dl + (id0 + id1 - 2.f * dl) * th1;
        float rden = __frcp_rn(den);
        float yy   = ich + ibh * (dl * th * th + id0 * th1) * rden;
        float num  = dl * dl * (id1 * th * th + 2.f * dl * th1
                                + id0 * (1.f - th) * (1.f - th));
        float lad  = __logf(num * rden * rden);

        if (inside) {
            zf[r * 48 + fb + fl] = yy;
            atomicAdd(&ldl[r], lad);
        }
    }
}

__global__ __launch_bounds__(512, 8) void maf_main(
    const float* __restrict__ x, const float* __restrict__ cond,
    const float* __restrict__ bh_all,
    const bf16* __restrict__ W0m, const bf16* __restrict__ Whm,
    const bf16* __restrict__ Wfm,
    const float* __restrict__ beff, const float* __restrict__ bfp,
    const float* __restrict__ Wcc,
    float* __restrict__ out, int B)
{
    extern __shared__ char smem[];
    float* zf    = (float*)(smem + SO_ZF);
    bf16*  hidA  = (bf16*)(smem + SO_HIDA);
    bf16*  pbuf  = (bf16*)(smem + SO_PBUF);
    float* condl = (float*)(smem + SO_COND);
    float* ldl   = (float*)(smem + SO_LD);

    const int t    = threadIdx.x;
    const int r0   = blockIdx.x * 32;
    const int w    = t >> 6;
    const int lane = t & 63;

    // init: zf (pad cols 45..47 = 0), cond, ld
    for (int i = t; i < 32 * 48; i += 512) {
        int r = i / 48, c = i - (i / 48) * 48;
        float v = 0.f;
        if (c < 45 && r0 + r < B) v = x[(size_t)(r0 + r) * 45 + c];
        zf[i] = v;
    }
    if (t < 32) {
        condl[t] = (r0 + t < B) ? cond[r0 + t] : 0.f;
        ldl[t]   = 0.f;
    }
    __syncthreads();

    #pragma unroll 1
    for (int b = 0; b < 6; ++b) {
        // input MADE layer: K=48 (padded from 45), A-frags from zf (f32)
        gemm32<3, 8, 0, true, 256>(zf, 48, W0m + b * 12288,
                                   beff + b * 256, Wcc + b * 256, condl,
                                   hidA, 264, w, lane, false);
        // 2 hidden layers, relu, in-place
        #pragma unroll 1
        for (int l = 0; l < 2; ++l)
            gemm32<16, 8, 1, false, 256>(hidA, 264, Whm + (b * 2 + l) * 65536,
                                         bh_all + (b * 2 + l) * 256, nullptr,
                                         nullptr, hidA, 264, w, lane, true);
        // params: 5 groups x 9 features (stride-24, cols 0..215 valid)
        #pragma unroll 1
        for (int g = 0; g < 5; ++g) {
            gemm32<16, 7, 2, false, 216>(hidA, 264,
                                         Wfm + (size_t)(b * 5 + g) * 57344,
                                         bfp + (b * 5 + g) * 224, nullptr,
                                         nullptr, pbuf, 216, w, lane, false);
            do_spline(g * 9, zf, pbuf, ldl, t);
            __syncthreads();
        }
    }

    if (t < 32 && r0 + t < B) {
        float s = 0.f;
        #pragma unroll
        for (int f = 0; f < 45; ++f) { float v = zf[t * 48 + f]; s += v * v; }
        out[r0 + t] = -0.5f * s - LOGZ + ldl[t];
    }
}

// ---------------- host entry ----------------
extern "C" void kernel_launch(void* const* d_in, const int* in_sizes, int n_in,
                              void* d_out, int out_size, void* d_ws, size_t ws_size,
                              hipStream_t stream)
{
    const float* x    = (const float*)d_in[0];
    const float* cond = (const float*)d_in[1];
    const float* W0   = (const float*)d_in[2];
    const float* b0   = (const float*)d_in[3];
    const float* Wc   = (const float*)d_in[4];
    const float* bc   = (const float*)d_in[5];
    const float* Wh   = (const float*)d_in[6];
    const float* bh   = (const float*)d_in[7];
    const float* Wf   = (const float*)d_in[8];
    const float* bfv  = (const float*)d_in[9];
    float* out = (float*)d_out;

    const int B = in_sizes[0] / 45;
    if (ws_size < (size_t)WS_NEED) return;   // fail loudly

    char* ws = (char*)d_ws;
    bf16*  W0m  = (bf16*)(ws + WS_W0M);
    bf16*  Whm  = (bf16*)(ws + WS_WHM);
    bf16*  Wfm  = (bf16*)(ws + WS_WFM);
    float* beff = (float*)(ws + WS_BEFF);
    float* bfp  = (float*)(ws + WS_BFP);
    float* Wcc  = (float*)(ws + WS_WCC);

    prep_all<<<(N_PREP + 255) / 256, 256, 0, stream>>>(
        W0, b0, Wc, bc, Wh, Wf, bfv, W0m, Whm, Wfm, beff, bfp, Wcc);

    (void)hipFuncSetAttribute((const void*)maf_main,
                              hipFuncAttributeMaxDynamicSharedMemorySize,
                              SMEM_BYTES);

    const int nwg = (B + 31) / 32;
    maf_main<<<nwg, 512, SMEM_BYTES, stream>>>(
        x, cond, bh, W0m, Whm, Wfm, beff, bfp, Wcc, out, B);
}